// Round 1
// baseline (58.354 us; speedup 1.0000x reference)
//
#include <hip/hip_runtime.h>

#define NB 16
#define T 16000
#define NF 64
#define TT 128
#define HALO 32
#define ROWS (TT + HALO)      // 160
#define RSU 36                // row stride in uints (72 bf16, padded from 64)
#define N_ITD 16
#define N_ILD 8

__device__ __forceinline__ unsigned int f2bf(float x) {
    unsigned int u = __float_as_uint(x);
    u += 0x7FFFu + ((u >> 16) & 1u);   // round-to-nearest-even
    return u >> 16;
}
__device__ __forceinline__ float bflo(unsigned int u) { return __uint_as_float(u << 16); }
__device__ __forceinline__ float bfhi(unsigned int u) { return __uint_as_float(u & 0xFFFF0000u); }

__global__ __launch_bounds__(TT) void biaural_kernel(const float* __restrict__ L,
                                                     const float* __restrict__ R,
                                                     float* __restrict__ out) {
    __shared__ unsigned int Lsh[ROWS * RSU];
    __shared__ unsigned int Rsh[ROWS * RSU];

    const int b = blockIdx.y;
    const int t0 = blockIdx.x * TT;
    const int tid = threadIdx.x;

    const float* __restrict__ Lb = L + (size_t)b * T * NF;
    const float* __restrict__ Rb = R + (size_t)b * T * NF;

    // ---- stage [t0-32, t0+127] x 64 as bf16 into LDS (coalesced float4 loads)
    for (int n = tid; n < ROWS * 16; n += TT) {
        const int row = n >> 4;        // 16 float4-chunks per row
        const int c4  = n & 15;
        const int gt  = t0 - HALO + row;
        float4 lv = make_float4(0.f, 0.f, 0.f, 0.f);
        float4 rv = lv;
        if (gt >= 0) {
            lv = *(const float4*)(Lb + (size_t)gt * NF + c4 * 4);
            rv = *(const float4*)(Rb + (size_t)gt * NF + c4 * 4);
        }
        uint2 lp, rp;
        lp.x = f2bf(lv.x) | (f2bf(lv.y) << 16);
        lp.y = f2bf(lv.z) | (f2bf(lv.w) << 16);
        rp.x = f2bf(rv.x) | (f2bf(rv.y) << 16);
        rp.y = f2bf(rv.z) | (f2bf(rv.w) << 16);
        const int idx = row * RSU + c4 * 2;
        *(uint2*)&Lsh[idx] = lp;
        *(uint2*)&Rsh[idx] = rp;
    }
    __syncthreads();

    // ---- each thread computes one output time step
    const int t = t0 + tid;
    const int crow = HALO + tid;

    float acc[N_ITD];
#pragma unroll
    for (int i = 0; i < N_ITD; ++i) acc[i] = 0.f;
    float sumL = 0.f, sumR = 0.f;

    const int OFF[8] = {2, 6, 11, 15, 19, 23, 28, 32};

#pragma unroll
    for (int f0 = 0; f0 < NF; f0 += 8) {
        const uint4 lc = *(const uint4*)&Lsh[crow * RSU + (f0 >> 1)];
        const uint4 rc = *(const uint4*)&Rsh[crow * RSU + (f0 >> 1)];
        float lcf[8], rcf[8];
        lcf[0] = bflo(lc.x); lcf[1] = bfhi(lc.x); lcf[2] = bflo(lc.y); lcf[3] = bfhi(lc.y);
        lcf[4] = bflo(lc.z); lcf[5] = bfhi(lc.z); lcf[6] = bflo(lc.w); lcf[7] = bfhi(lc.w);
        rcf[0] = bflo(rc.x); rcf[1] = bfhi(rc.x); rcf[2] = bflo(rc.y); rcf[3] = bfhi(rc.y);
        rcf[4] = bflo(rc.z); rcf[5] = bfhi(rc.z); rcf[6] = bflo(rc.w); rcf[7] = bfhi(rc.w);
#pragma unroll
        for (int j = 0; j < 8; ++j) { sumL += lcf[j]; sumR += rcf[j]; }

#pragma unroll
        for (int k = 0; k < 8; ++k) {
            const int off = OFF[k];
            // positive delay d = off  -> di = 8+k : L[t-off] . R[t]
            const uint4 la = *(const uint4*)&Lsh[(crow - off) * RSU + (f0 >> 1)];
            float laf[8];
            laf[0] = bflo(la.x); laf[1] = bfhi(la.x); laf[2] = bflo(la.y); laf[3] = bfhi(la.y);
            laf[4] = bflo(la.z); laf[5] = bfhi(la.z); laf[6] = bflo(la.w); laf[7] = bfhi(la.w);
#pragma unroll
            for (int j = 0; j < 8; ++j) acc[8 + k] += laf[j] * rcf[j];
            // negative delay |d| = off -> di = 7-k : L[t] . R[t-off]
            const uint4 ra = *(const uint4*)&Rsh[(crow - off) * RSU + (f0 >> 1)];
            float raf[8];
            raf[0] = bflo(ra.x); raf[1] = bfhi(ra.x); raf[2] = bflo(ra.y); raf[3] = bfhi(ra.y);
            raf[4] = bflo(ra.z); raf[5] = bfhi(ra.z); raf[6] = bflo(ra.w); raf[7] = bfhi(ra.w);
#pragma unroll
            for (int j = 0; j < 8; ++j) acc[7 - k] += lcf[j] * raf[j];
        }
    }

    // ---- write ITD: [B,T,16], contiguous 64 B per thread
    float* oitd = out + ((size_t)b * T + t) * N_ITD;
#pragma unroll
    for (int q = 0; q < 4; ++q) {
        float4 v = make_float4(acc[q * 4 + 0], acc[q * 4 + 1], acc[q * 4 + 2], acc[q * 4 + 3]);
        *(float4*)(oitd + q * 4) = v;
    }

    // ---- ILD: [B,T,8] appended after ITD block
    const float ild = (sumL - sumR) / (sumL + sumR + 1e-6f);
    const float PREFS[8] = {-1.f, -0.71428573f, -0.42857143f, -0.14285714f,
                            0.14285715f, 0.42857143f, 0.71428573f, 1.f};
    float ov[8];
#pragma unroll
    for (int j = 0; j < 8; ++j) {
        const float z = (ild - PREFS[j]) * (1.0f / 0.3f);
        ov[j] = __expf(-0.5f * z * z);
    }
    float* oild = out + (size_t)NB * T * N_ITD + ((size_t)b * T + t) * N_ILD;
    *(float4*)(oild + 0) = make_float4(ov[0], ov[1], ov[2], ov[3]);
    *(float4*)(oild + 4) = make_float4(ov[4], ov[5], ov[6], ov[7]);
}

extern "C" void kernel_launch(void* const* d_in, const int* in_sizes, int n_in,
                              void* d_out, int out_size, void* d_ws, size_t ws_size,
                              hipStream_t stream) {
    const float* L = (const float*)d_in[0];
    const float* R = (const float*)d_in[1];
    float* out = (float*)d_out;
    dim3 grid(T / TT, NB);
    biaural_kernel<<<grid, dim3(TT), 0, stream>>>(L, R, out);
}

// Round 2
// 36.429 us; speedup vs baseline: 1.6019x; 1.6019x over previous
//
#include <hip/hip_runtime.h>

#define NB 16
#define T 16000
#define NF 64
#define TILE 256
#define TT 256
#define HALO 32
#define ROWS (TILE + HALO)    // 288
#define RSU 36                // combined row stride in dwords: L dw 0..15, R dw 16..31, pad 4
#define N_ITD 16
#define N_ILD 8

typedef _Float16 half2_t __attribute__((ext_vector_type(2)));

__device__ __forceinline__ unsigned int pk2h(float a, float b) {
    half2_t h;
    h.x = (_Float16)a;
    h.y = (_Float16)b;
    return __builtin_bit_cast(unsigned int, h);
}
__device__ __forceinline__ float dot2(unsigned int a, unsigned int b, float c) {
    return __builtin_amdgcn_fdot2(__builtin_bit_cast(half2_t, a),
                                  __builtin_bit_cast(half2_t, b), c, false);
}

__global__ __launch_bounds__(TT, 3) void biaural_kernel(const float* __restrict__ L,
                                                        const float* __restrict__ R,
                                                        float* __restrict__ out) {
    __shared__ unsigned int sh[ROWS * RSU];   // 41472 B -> 3 blocks/CU

    const int b = blockIdx.y;
    const int t0 = blockIdx.x * TILE;
    const int tid = threadIdx.x;

    const float* __restrict__ Lb = L + (size_t)b * T * NF;
    const float* __restrict__ Rb = R + (size_t)b * T * NF;

    float acc[N_ITD];
#pragma unroll
    for (int i = 0; i < N_ITD; ++i) acc[i] = 0.f;
    float sumL = 0.f, sumR = 0.f;

    const int OFF[8] = {2, 6, 11, 15, 19, 23, 28, 32};
    const unsigned int ONE2 = 0x3C003C00u;   // (1.0h, 1.0h)
    const int crowbase = (HALO + tid) * RSU;

#pragma unroll
    for (int pass = 0; pass < 2; ++pass) {
        const int pf = pass * 32;            // float offset within the 64-ch row
        if (pass) __syncthreads();           // protect LDS reuse

        // ---- stage [t0-32, t0+255] x 32ch of both ears as f16 (b128 writes)
        for (int n = tid; n < ROWS * 4; n += TT) {
            const int row = n >> 2;
            const int c = n & 3;             // 8-float chunk within the 32-ch slab
            const int gt = t0 - HALO + row;
            uint4 pl = make_uint4(0u, 0u, 0u, 0u);
            uint4 pr = make_uint4(0u, 0u, 0u, 0u);
            if (gt >= 0 && gt < T) {
                const float* lp = Lb + (size_t)gt * NF + pf + c * 8;
                const float* rp = Rb + (size_t)gt * NF + pf + c * 8;
                float4 a0 = *(const float4*)lp;
                float4 a1 = *(const float4*)(lp + 4);
                float4 b0 = *(const float4*)rp;
                float4 b1 = *(const float4*)(rp + 4);
                pl = make_uint4(pk2h(a0.x, a0.y), pk2h(a0.z, a0.w),
                                pk2h(a1.x, a1.y), pk2h(a1.z, a1.w));
                pr = make_uint4(pk2h(b0.x, b0.y), pk2h(b0.z, b0.w),
                                pk2h(b1.x, b1.y), pk2h(b1.z, b1.w));
            }
            *(uint4*)&sh[row * RSU + c * 4] = pl;
            *(uint4*)&sh[row * RSU + 16 + c * 4] = pr;
        }
        __syncthreads();

        // ---- compute: 4 chunks of 8 channels
#pragma unroll
        for (int c = 0; c < 4; ++c) {
            const uint4 lc = *(const uint4*)&sh[crowbase + c * 4];
            const uint4 rc = *(const uint4*)&sh[crowbase + 16 + c * 4];
            sumL = dot2(lc.x, ONE2, sumL); sumL = dot2(lc.y, ONE2, sumL);
            sumL = dot2(lc.z, ONE2, sumL); sumL = dot2(lc.w, ONE2, sumL);
            sumR = dot2(rc.x, ONE2, sumR); sumR = dot2(rc.y, ONE2, sumR);
            sumR = dot2(rc.z, ONE2, sumR); sumR = dot2(rc.w, ONE2, sumR);
#pragma unroll
            for (int k = 0; k < 8; ++k) {
                const int rb = crowbase - OFF[k] * RSU;
                const uint4 la = *(const uint4*)&sh[rb + c * 4];
                acc[8 + k] = dot2(la.x, rc.x, acc[8 + k]);
                acc[8 + k] = dot2(la.y, rc.y, acc[8 + k]);
                acc[8 + k] = dot2(la.z, rc.z, acc[8 + k]);
                acc[8 + k] = dot2(la.w, rc.w, acc[8 + k]);
                const uint4 ra = *(const uint4*)&sh[rb + 16 + c * 4];
                acc[7 - k] = dot2(lc.x, ra.x, acc[7 - k]);
                acc[7 - k] = dot2(lc.y, ra.y, acc[7 - k]);
                acc[7 - k] = dot2(lc.z, ra.z, acc[7 - k]);
                acc[7 - k] = dot2(lc.w, ra.w, acc[7 - k]);
            }
        }
    }

    const int t = t0 + tid;
    if (t < T) {
        // ---- ITD: [B,T,16]
        float* oitd = out + ((size_t)b * T + t) * N_ITD;
#pragma unroll
        for (int q = 0; q < 4; ++q) {
            *(float4*)(oitd + q * 4) =
                make_float4(acc[q * 4 + 0], acc[q * 4 + 1], acc[q * 4 + 2], acc[q * 4 + 3]);
        }

        // ---- ILD: [B,T,8] after the ITD block
        const float ild = (sumL - sumR) / (sumL + sumR + 1e-6f);
        const float PREFS[8] = {-1.f, -0.71428573f, -0.42857143f, -0.14285714f,
                                0.14285715f, 0.42857143f, 0.71428573f, 1.f};
        float ov[8];
#pragma unroll
        for (int j = 0; j < 8; ++j) {
            const float z = (ild - PREFS[j]) * (1.0f / 0.3f);
            ov[j] = __expf(-0.5f * z * z);
        }
        float* oild = out + (size_t)NB * T * N_ITD + ((size_t)b * T + t) * N_ILD;
        *(float4*)(oild + 0) = make_float4(ov[0], ov[1], ov[2], ov[3]);
        *(float4*)(oild + 4) = make_float4(ov[4], ov[5], ov[6], ov[7]);
    }
}

extern "C" void kernel_launch(void* const* d_in, const int* in_sizes, int n_in,
                              void* d_out, int out_size, void* d_ws, size_t ws_size,
                              hipStream_t stream) {
    const float* L = (const float*)d_in[0];
    const float* R = (const float*)d_in[1];
    float* out = (float*)d_out;
    dim3 grid((T + TILE - 1) / TILE, NB);
    biaural_kernel<<<grid, dim3(TT), 0, stream>>>(L, R, out);
}

// Round 3
// 35.417 us; speedup vs baseline: 1.6476x; 1.0286x over previous
//
#include <hip/hip_runtime.h>

#define NB 16
#define T 16000
#define NF 64
#define TILE 252              // output timesteps per block
#define TT 256                // threads per block
#define HALO 32
#define ROWS (TILE + HALO)    // 284
#define RSU 36                // combined row stride in dwords: L dw 0..15, R dw 16..31, pad 4
#define N_ITD 16
#define N_ILD 8

typedef _Float16 half2_t __attribute__((ext_vector_type(2)));

__device__ __forceinline__ unsigned int pk2h(float a, float b) {
    half2_t h;
    h.x = (_Float16)a;
    h.y = (_Float16)b;
    return __builtin_bit_cast(unsigned int, h);
}
__device__ __forceinline__ float dot2(unsigned int a, unsigned int b, float c) {
    return __builtin_amdgcn_fdot2(__builtin_bit_cast(half2_t, a),
                                  __builtin_bit_cast(half2_t, b), c, false);
}

// LDS = 284*36*4 = 40896 B -> 4 blocks/CU = 16 waves/CU (50% occupancy)
__global__ __launch_bounds__(TT, 4) void biaural_kernel(const float* __restrict__ L,
                                                        const float* __restrict__ R,
                                                        float* __restrict__ out) {
    __shared__ unsigned int sh[ROWS * RSU];

    const int b = blockIdx.y;
    const int t0 = blockIdx.x * TILE;
    const int tid = threadIdx.x;

    const float* __restrict__ Lb = L + (size_t)b * T * NF;
    const float* __restrict__ Rb = R + (size_t)b * T * NF;

    float acc[N_ITD];
#pragma unroll
    for (int i = 0; i < N_ITD; ++i) acc[i] = 0.f;
    float sumL = 0.f, sumR = 0.f;

    const int OFF[8] = {2, 6, 11, 15, 19, 23, 28, 32};
    const unsigned int ONE2 = 0x3C003C00u;   // (1.0h, 1.0h)
    const int ct = (tid < TILE) ? tid : (TILE - 1);   // clamp idle threads into bounds
    const int crowbase = (HALO + ct) * RSU;

#pragma unroll
    for (int pass = 0; pass < 2; ++pass) {
        const int pf = pass * 32;            // float offset within the 64-ch row
        if (pass) __syncthreads();           // protect LDS reuse

        // ---- stage [t0-32, t0+TILE-1] x 32ch of both ears as f16 (b128 writes)
        for (int n = tid; n < ROWS * 4; n += TT) {
            const int row = n >> 2;
            const int c = n & 3;             // 8-float chunk within the 32-ch slab
            const int gt = t0 - HALO + row;
            uint4 pl = make_uint4(0u, 0u, 0u, 0u);
            uint4 pr = make_uint4(0u, 0u, 0u, 0u);
            if (gt >= 0 && gt < T) {
                const float* lp = Lb + (size_t)gt * NF + pf + c * 8;
                const float* rp = Rb + (size_t)gt * NF + pf + c * 8;
                float4 a0 = *(const float4*)lp;
                float4 a1 = *(const float4*)(lp + 4);
                float4 b0 = *(const float4*)rp;
                float4 b1 = *(const float4*)(rp + 4);
                pl = make_uint4(pk2h(a0.x, a0.y), pk2h(a0.z, a0.w),
                                pk2h(a1.x, a1.y), pk2h(a1.z, a1.w));
                pr = make_uint4(pk2h(b0.x, b0.y), pk2h(b0.z, b0.w),
                                pk2h(b1.x, b1.y), pk2h(b1.z, b1.w));
            }
            *(uint4*)&sh[row * RSU + c * 4] = pl;
            *(uint4*)&sh[row * RSU + 16 + c * 4] = pr;
        }
        __syncthreads();

        // ---- compute: 4 chunks of 8 channels
#pragma unroll
        for (int c = 0; c < 4; ++c) {
            const uint4 lc = *(const uint4*)&sh[crowbase + c * 4];
            const uint4 rc = *(const uint4*)&sh[crowbase + 16 + c * 4];
            sumL = dot2(lc.x, ONE2, sumL); sumL = dot2(lc.y, ONE2, sumL);
            sumL = dot2(lc.z, ONE2, sumL); sumL = dot2(lc.w, ONE2, sumL);
            sumR = dot2(rc.x, ONE2, sumR); sumR = dot2(rc.y, ONE2, sumR);
            sumR = dot2(rc.z, ONE2, sumR); sumR = dot2(rc.w, ONE2, sumR);
#pragma unroll
            for (int k = 0; k < 8; ++k) {
                const int rb = crowbase - OFF[k] * RSU;
                const uint4 la = *(const uint4*)&sh[rb + c * 4];
                acc[8 + k] = dot2(la.x, rc.x, acc[8 + k]);
                acc[8 + k] = dot2(la.y, rc.y, acc[8 + k]);
                acc[8 + k] = dot2(la.z, rc.z, acc[8 + k]);
                acc[8 + k] = dot2(la.w, rc.w, acc[8 + k]);
                const uint4 ra = *(const uint4*)&sh[rb + 16 + c * 4];
                acc[7 - k] = dot2(lc.x, ra.x, acc[7 - k]);
                acc[7 - k] = dot2(lc.y, ra.y, acc[7 - k]);
                acc[7 - k] = dot2(lc.z, ra.z, acc[7 - k]);
                acc[7 - k] = dot2(lc.w, ra.w, acc[7 - k]);
            }
        }
    }

    const int t = t0 + tid;
    if (tid < TILE && t < T) {
        // ---- ITD: [B,T,16]
        float* oitd = out + ((size_t)b * T + t) * N_ITD;
#pragma unroll
        for (int q = 0; q < 4; ++q) {
            *(float4*)(oitd + q * 4) =
                make_float4(acc[q * 4 + 0], acc[q * 4 + 1], acc[q * 4 + 2], acc[q * 4 + 3]);
        }

        // ---- ILD: [B,T,8] after the ITD block
        const float ild = (sumL - sumR) / (sumL + sumR + 1e-6f);
        const float PREFS[8] = {-1.f, -0.71428573f, -0.42857143f, -0.14285714f,
                                0.14285715f, 0.42857143f, 0.71428573f, 1.f};
        float ov[8];
#pragma unroll
        for (int j = 0; j < 8; ++j) {
            const float z = (ild - PREFS[j]) * (1.0f / 0.3f);
            ov[j] = __expf(-0.5f * z * z);
        }
        float* oild = out + (size_t)NB * T * N_ITD + ((size_t)b * T + t) * N_ILD;
        *(float4*)(oild + 0) = make_float4(ov[0], ov[1], ov[2], ov[3]);
        *(float4*)(oild + 4) = make_float4(ov[4], ov[5], ov[6], ov[7]);
    }
}

extern "C" void kernel_launch(void* const* d_in, const int* in_sizes, int n_in,
                              void* d_out, int out_size, void* d_ws, size_t ws_size,
                              hipStream_t stream) {
    const float* L = (const float*)d_in[0];
    const float* R = (const float*)d_in[1];
    float* out = (float*)d_out;
    dim3 grid((T + TILE - 1) / TILE, NB);
    biaural_kernel<<<grid, dim3(TT), 0, stream>>>(L, R, out);
}